// Round 16
// baseline (141.139 us; speedup 1.0000x reference)
//
#include <hip/hip_runtime.h>

// CrossAttention on MI355X (gfx950), round 16.
// B=8 SQ=4096 SKV=77 DE=512 DC=768 H=8 DH=64.
// R16: qproj geometry 128x128 -> 64x128 (2048 blocks). Wave owns 32 rows x
// 1 head -> tail = 2 rg chains (was 4); LDS 24576 -> 6 blocks/CU resident of
// 8 queued -> block turnover overlaps GEMM and tail phases. Staging 3
// GLDS/wave/step (A x1, B x2), counted vmcnt(3). ogemm/kv/cvt/wtrans
// unchanged from R15.

typedef __attribute__((ext_vector_type(8))) __bf16 bf16x8;
typedef __attribute__((ext_vector_type(4))) float f32x4;

#define DEVI static __device__ __forceinline__

typedef __attribute__((address_space(3))) void lds_void_t;
typedef const __attribute__((address_space(1))) void gbl_void_t;
#define GLDS16(gsrc, ldst) \
  __builtin_amdgcn_global_load_lds((gbl_void_t*)(gsrc), (lds_void_t*)(ldst), 16, 0, 0)

DEVI unsigned short f2bf(float f) {
  unsigned int u = __float_as_uint(f);
  u += 0x7FFFu + ((u >> 16) & 1u);   // round-to-nearest-even
  return (unsigned short)(u >> 16);
}

DEVI unsigned int pack2bf(float a, float b) {
  return (unsigned int)f2bf(a) | ((unsigned int)f2bf(b) << 16);
}

// ---------------------------------------------------------------------------
// latent fp32 -> bf16, 8 elems/thread (standalone, proven)
// ---------------------------------------------------------------------------
__global__ __launch_bounds__(256) void cvt_bf16_kernel(const float* __restrict__ in,
                                                       unsigned int* __restrict__ out4) {
  size_t i = (size_t)blockIdx.x * 256 + threadIdx.x;
  const float4* in4 = (const float4*)in;
  float4 a = in4[2 * i];
  float4 b = in4[2 * i + 1];
  uint4 o;
  o.x = pack2bf(a.x, a.y);
  o.y = pack2bf(a.z, a.w);
  o.z = pack2bf(b.x, b.y);
  o.w = pack2bf(b.z, b.w);
  *(uint4*)(out4 + 4 * i) = o;
}

// ---------------------------------------------------------------------------
// All 4 weight transposes in one launch (homogeneous body, proven).
// ---------------------------------------------------------------------------
__global__ __launch_bounds__(256) void wtrans_all_kernel(
    const float* __restrict__ wq, const float* __restrict__ wk,
    const float* __restrict__ wv, const float* __restrict__ wo,
    unsigned short* __restrict__ wqT, unsigned short* __restrict__ wkT,
    unsigned short* __restrict__ wvT, unsigned short* __restrict__ woT) {
  __shared__ float tile[32][33];
  int bid = blockIdx.x;
  int tid = threadIdx.x;
  const float* in;
  unsigned short* out;
  int K, r;
  if (bid < 256)       { in = wq; out = wqT; K = 512; r = bid; }
  else if (bid < 640)  { in = wk; out = wkT; K = 768; r = bid - 256; }
  else if (bid < 1024) { in = wv; out = wvT; K = 768; r = bid - 640; }
  else                 { in = wo; out = woT; K = 512; r = bid - 1024; }
  int n0 = (r & 15) * 32, k0 = (r >> 4) * 32;
  int tx = tid & 31, ty = tid >> 5;
#pragma unroll
  for (int j = 0; j < 4; ++j)
    tile[ty * 4 + j][tx] = in[(size_t)(k0 + ty * 4 + j) * 512 + n0 + tx];
  __syncthreads();
#pragma unroll
  for (int j = 0; j < 4; ++j)
    out[(size_t)(n0 + ty * 4 + j) * K + k0 + tx] = f2bf(tile[tx][ty * 4 + j]);
}

// ---------------------------------------------------------------------------
// K/V projection (standalone, proven)
// ---------------------------------------------------------------------------
__global__ __launch_bounds__(256) void kv_proj_kernel(const float* __restrict__ ctx,
                                                      const unsigned short* __restrict__ wkT,
                                                      const unsigned short* __restrict__ wvT,
                                                      const float* __restrict__ bk,
                                                      const float* __restrict__ bv,
                                                      unsigned short* __restrict__ Kp,
                                                      unsigned short* __restrict__ Vt) {
  __shared__ __align__(16) unsigned short As[64][40];
  __shared__ __align__(16) unsigned short Bs[64][40];
  int bid = blockIdx.x;
  int sel = bid / 80;
  int rem = bid % 80;
  int mt = rem / 8, nt = rem % 8;
  const unsigned short* wT = sel ? wvT : wkT;
  const float* bias = sel ? bv : bk;
  int tid = threadIdx.x;
  int l = tid & 63, w = tid >> 6;
  int lr = l & 15, lg = l >> 4;

  f32x4 acc[4] = {};
  for (int k0 = 0; k0 < 768; k0 += 32) {
#pragma unroll
    for (int it = 0; it < 2; ++it) {
      int idx4 = it * 256 + tid;
      int r = idx4 >> 3, q4 = idx4 & 7;
      int m = mt * 64 + r;
      float4 v = {0.f, 0.f, 0.f, 0.f};
      if (m < 616) v = *(const float4*)(ctx + (size_t)m * 768 + k0 + q4 * 4);
      ushort4 o;
      o.x = f2bf(v.x); o.y = f2bf(v.y); o.z = f2bf(v.z); o.w = f2bf(v.w);
      *(ushort4*)&As[r][q4 * 4] = o;
    }
    {
      int c = tid >> 2, q8 = tid & 3;
      *(uint4*)&Bs[c][q8 * 8] =
          *(const uint4*)(wT + (size_t)(nt * 64 + c) * 768 + k0 + q8 * 8);
    }
    __syncthreads();
    bf16x8 a = *(const bf16x8*)&As[w * 16 + lr][lg * 8];
#pragma unroll
    for (int n = 0; n < 4; ++n) {
      bf16x8 bb = *(const bf16x8*)&Bs[n * 16 + lr][lg * 8];
      acc[n] = __builtin_amdgcn_mfma_f32_16x16x32_bf16(a, bb, acc[n], 0, 0, 0);
    }
    __syncthreads();
  }
#pragma unroll
  for (int n = 0; n < 4; ++n) {
#pragma unroll
    for (int reg = 0; reg < 4; ++reg) {
      int m = mt * 64 + w * 16 + lg * 4 + reg;
      if (m < 616) {
        int bI = m / 77, s = m % 77;
        int col = nt * 64 + n * 16 + lr;
        int h = col >> 6, d = col & 63;
        float v = acc[n][reg] + bias[col];
        if (sel == 0)
          Kp[(((size_t)(bI * 8 + h)) * 80 + s) * 64 + d] = f2bf(v);
        else
          Vt[(((size_t)(bI * 8 + h)) * 64 + d) * 96 + s] = f2bf(v);
      }
    }
  }
}

// ---------------------------------------------------------------------------
// qproj 64x128 K-step: A [64][32] @ +0, B [128][32] @ +2048; buffer c at
// c*6144 elems. 3 GLDS/wave/step; vmcnt(3) steady.
// ---------------------------------------------------------------------------
#define QSTEP64(t, boff)                                                      \
  {                                                                           \
    if ((t) < 15)                                                             \
      asm volatile("s_waitcnt vmcnt(3)" ::: "memory");                        \
    else                                                                      \
      asm volatile("s_waitcnt vmcnt(0)" ::: "memory");                        \
    __builtin_amdgcn_s_barrier();                                             \
    __builtin_amdgcn_sched_barrier(0);                                        \
    const unsigned short* bufA = smem + (boff);                               \
    const unsigned short* bufB = bufA + 2048;                                 \
    const int swz = (lr >> 1) & 3;                                            \
    bf16x8 af[2], bv8[4];                                                     \
    _Pragma("unroll") for (int m = 0; m < 2; ++m)                             \
        af[m] = *(const bf16x8*)&bufA[(wr + m * 16 + lr) * 32 +               \
                                      (lg ^ swz) * 8];                        \
    _Pragma("unroll") for (int n = 0; n < 4; ++n)                             \
        bv8[n] = *(const bf16x8*)&bufB[(wc + n * 16 + lr) * 32 +              \
                                       (lg ^ swz) * 8];                       \
    asm volatile("s_waitcnt lgkmcnt(0)" ::: "memory");                        \
    __builtin_amdgcn_sched_barrier(0);                                        \
    __builtin_amdgcn_s_barrier();                                             \
    if ((t) <= 13) {                                                          \
      int nk = ((t) + 2) * 32;                                                \
      GLDS16(gA + nk, smem + (boff) + w * 512);                               \
      GLDS16(gB + nk, smem + (boff) + 2048 + w * 1024);                       \
      GLDS16(gB + nk + 16 * 512, smem + (boff) + 2048 + w * 1024 + 512);      \
    }                                                                         \
    _Pragma("unroll") for (int m = 0; m < 2; ++m)                             \
        _Pragma("unroll") for (int n = 0; n < 4; ++n)                         \
            acc[m][n] = __builtin_amdgcn_mfma_f32_16x16x32_bf16(              \
                af[m], bv8[n], acc[m][n], 0, 0, 0);                           \
  }

// ---------------------------------------------------------------------------
// FUSED Q-proj + attention, 64x128 tile, 2048 blocks. Wave = 32 rows x 1
// head; tail = 2 rg chains. LDS 24576 B -> 6 blocks/CU resident (8 queued).
// ---------------------------------------------------------------------------
__global__ __launch_bounds__(256, 6) void qproj_attn_kernel(
    const unsigned short* __restrict__ A, const unsigned short* __restrict__ BT,
    const float* __restrict__ bias, const unsigned short* __restrict__ Kp,
    const unsigned short* __restrict__ Vt, unsigned short* __restrict__ Oq) {
  __shared__ __align__(16) unsigned short smem[12288];  // 24576 B

  int bid = ((blockIdx.x & 7) << 8) | (blockIdx.x >> 3);  // XCD swizzle, 2048
  size_t mbase = (size_t)(bid >> 2) * 64;
  int nbase = (bid & 3) * 128;
  int tid = threadIdx.x;
  int l = tid & 63, w = tid >> 6;
  int lr = l & 15, lg = l >> 4;
  int wr = (w >> 1) * 32;   // m-offset (wave owns 32 rows)
  int wc = (w & 1) * 64;    // n-offset (wave owns 64 cols = 1 head)

  // A: wave w stages rows w*16+(l>>2); pre-swizzled slot (l&3)^((l>>3)&3)
  const unsigned short* gA = A + (mbase + w * 16 + (l >> 2)) * 512 +
                             (((l & 3) ^ ((l >> 3) & 3))) * 8;
  // B: wave w stages rows w*32+(l>>2) (+16)
  const unsigned short* gB = BT + (size_t)(nbase + w * 32 + (l >> 2)) * 512 +
                             (((l & 3) ^ ((l >> 3) & 3))) * 8;

  // prologue: batch 0 -> buf0, batch 1 -> buf1 (A, B, B each)
  GLDS16(gA, smem + w * 512);
  GLDS16(gB, smem + 2048 + w * 1024);
  GLDS16(gB + 16 * 512, smem + 2048 + w * 1024 + 512);
  GLDS16(gA + 32, smem + 6144 + w * 512);
  GLDS16(gB + 32, smem + 6144 + 2048 + w * 1024);
  GLDS16(gB + 32 + 16 * 512, smem + 6144 + 2048 + w * 1024 + 512);

  f32x4 acc[2][4] = {};
#pragma unroll 1
  for (int t = 0; t < 16; t += 2) {
    QSTEP64(t, 0);
    QSTEP64(t + 1, 6144);
  }

  // ---- epilogue: Q 32x64 quadrant -> wave-private LDS (transpose), +bias ----
  // Step-15's second barrier guaranteed all waves' ds_reads complete.
  unsigned short* Qme = smem + w * 2304;  // [32][72]
  float bb[4];
#pragma unroll
  for (int n = 0; n < 4; ++n) bb[n] = bias[nbase + wc + n * 16 + lr];
#pragma unroll
  for (int m = 0; m < 2; ++m)
#pragma unroll
    for (int n = 0; n < 4; ++n)
#pragma unroll
      for (int reg = 0; reg < 4; ++reg)
        Qme[(m * 16 + lg * 4 + reg) * 72 + n * 16 + lr] = f2bf(acc[m][n][reg] + bb[n]);

  bf16x8 qf[2][2];
#pragma unroll
  for (int rg = 0; rg < 2; ++rg) {
    qf[rg][0] = *(const bf16x8*)&Qme[(rg * 16 + lr) * 72 + lg * 8];
    qf[rg][1] = *(const bf16x8*)&Qme[(rg * 16 + lr) * 72 + 32 + lg * 8];
  }

  // wave-private P inside this wave's dead Qw region (16 x 104 bf16)
  unsigned short* Pme = Qme;
  for (int z = l; z < 256; z += 64) Pme[(z >> 4) * 104 + 80 + (z & 15)] = 0;

  // ---- wave-local attention: 32 q-rows x head h ----
  int b = (int)(mbase >> 12);
  int h = (bid & 3) * 2 + (w & 1);
  const unsigned short* Kph = Kp + (size_t)(b * 8 + h) * (80 * 64);
  const unsigned short* Vth = Vt + (size_t)(b * 8 + h) * (64 * 96);

  const float C = 0.125f * 1.44269504088896f;  // 1/sqrt(64) * log2(e)

  auto QK = [&](int rg, f32x4* s) {
#pragma unroll
    for (int t = 0; t < 5; ++t) {
      const unsigned short* kr = Kph + (t * 16 + lr) * 64 + lg * 8;
      bf16x8 k0 = *(const bf16x8*)kr;
      bf16x8 k1 = *(const bf16x8*)(kr + 32);
      s[t] = __builtin_amdgcn_mfma_f32_16x16x32_bf16(qf[rg][0], k0, s[t], 0, 0, 0);
      s[t] = __builtin_amdgcn_mfma_f32_16x16x32_bf16(qf[rg][1], k1, s[t], 0, 0, 0);
    }
    if (lr >= 13) {  // cols 64+lr >= 77 are pad
      s[4][0] = -1e30f; s[4][1] = -1e30f; s[4][2] = -1e30f; s[4][3] = -1e30f;
    }
  };

  f32x4 sc[5] = {};
  QK(0, sc);
#pragma unroll
  for (int rg = 0; rg < 2; ++rg) {
    float mx[4];
#pragma unroll
    for (int r = 0; r < 4; ++r)
      mx[r] = fmaxf(fmaxf(fmaxf(sc[0][r], sc[1][r]), fmaxf(sc[2][r], sc[3][r])), sc[4][r]);
#pragma unroll
    for (int d = 1; d < 16; d <<= 1)
#pragma unroll
      for (int r = 0; r < 4; ++r) mx[r] = fmaxf(mx[r], __shfl_xor(mx[r], d, 64));
    float p[5][4];
#pragma unroll
    for (int t = 0; t < 5; ++t)
#pragma unroll
      for (int r = 0; r < 4; ++r) p[t][r] = exp2f((sc[t][r] - mx[r]) * C);
#pragma unroll
    for (int t = 0; t < 5; ++t)
#pragma unroll
      for (int r = 0; r < 4; ++r)
        Pme[(lg * 4 + r) * 104 + t * 16 + lr] = f2bf(p[t][r]);

    float sm[4];
#pragma unroll
    for (int r = 0; r < 4; ++r)
      sm[r] = p[0][r] + p[1][r] + p[2][r] + p[3][r] + p[4][r];
#pragma unroll
    for (int d = 1; d < 16; d <<= 1)
#pragma unroll
      for (int r = 0; r < 4; ++r) sm[r] += __shfl_xor(sm[r], d, 64);
    float rs[4];
#pragma unroll
    for (int r = 0; r < 4; ++r) rs[r] = 1.0f / sm[r];

    f32x4 sn[5] = {};
    if (rg < 1) QK(rg + 1, sn);

    bf16x8 ap[3];
#pragma unroll
    for (int c = 0; c < 3; ++c) ap[c] = *(const bf16x8*)&Pme[lr * 104 + c * 32 + lg * 8];
#pragma unroll
    for (int ct = 0; ct < 4; ++ct) {
      f32x4 o = {};
#pragma unroll
      for (int c = 0; c < 3; ++c) {
        bf16x8 vv = *(const bf16x8*)(Vth + (size_t)(ct * 16 + lr) * 96 + c * 32 + lg * 8);
        o = __builtin_amdgcn_mfma_f32_16x16x32_bf16(ap[c], vv, o, 0, 0, 0);
      }
#pragma unroll
      for (int reg = 0; reg < 4; ++reg)
        Oq[(mbase + wr + rg * 16 + lg * 4 + reg) * 512 + nbase + wc + ct * 16 + lr] =
            f2bf(o[reg] * rs[reg]);
    }
#pragma unroll
    for (int t = 0; t < 5; ++t) sc[t] = sn[t];
  }
}

// ---------------------------------------------------------------------------
// O-proj GEMM (unchanged R12/R15): 128x128, bf16 swizzled counted-vmcnt.
// ---------------------------------------------------------------------------
#define KSTEP(t, boff)                                                        \
  {                                                                           \
    if ((t) < 15)                                                             \
      asm volatile("s_waitcnt vmcnt(4)" ::: "memory");                        \
    else                                                                      \
      asm volatile("s_waitcnt vmcnt(0)" ::: "memory");                        \
    __builtin_amdgcn_s_barrier();                                             \
    __builtin_amdgcn_sched_barrier(0);                                        \
    const unsigned short* bufA = smem + (boff);                               \
    const unsigned short* bufB = bufA + 4096;                                 \
    const int swB = (lr >> 1) & 3;                                            \
    bf16x8 af[4], bv8[4];                                                     \
    _Pragma("unroll") for (int m = 0; m < 4; ++m)                             \
        af[m] = *(const bf16x8*)&bufA[(wr + m * 16 + lr) * 32 +               \
                                      (lg ^ swB) * 8];                        \
    _Pragma("unroll") for (int n = 0; n < 4; ++n)                             \
        bv8[n] = *(const bf16x8*)&bufB[(wc + n * 16 + lr) * 32 +              \
                                       (lg ^ swB) * 8];                       \
    asm volatile("s_waitcnt lgkmcnt(0)" ::: "memory");                        \
    __builtin_amdgcn_sched_barrier(0);                                        \
    __builtin_amdgcn_s_barrier();                                             \
    if ((t) <= 13) {                                                          \
      int nk = ((t) + 2) * 32;                                                \
      GLDS16(gA + nk, smem + (boff) + w * 1024);                              \
      GLDS16(gA + nk + 16 * 512, smem + (boff) + w * 1024 + 512);             \
      GLDS16(gB + nk, smem + (boff) + 4096 + w * 1024);                       \
      GLDS16(gB + nk + 16 * 512, smem + (boff) + 4096 + w * 1024 + 512);      \
    }                                                                         \
    _Pragma("unroll") for (int m = 0; m < 4; ++m)                             \
        _Pragma("unroll") for (int n = 0; n < 4; ++n)                         \
            acc[m][n] = __builtin_amdgcn_mfma_f32_16x16x32_bf16(              \
                af[m], bv8[n], acc[m][n], 0, 0, 0);                           \
  }

__global__ __launch_bounds__(256) void gemm512_glds_kernel(
    const unsigned short* __restrict__ A, const unsigned short* __restrict__ BT,
    const float* __restrict__ bias, float* __restrict__ Out) {
  __shared__ __align__(16) unsigned short smem[16384];  // 32 KB
  int bid = ((blockIdx.x & 7) << 7) | (blockIdx.x >> 3);  // XCD swizzle
  size_t mbase = (size_t)(bid >> 2) * 128;
  int nbase = (bid & 3) * 128;
  int tid = threadIdx.x;
  int l = tid & 63, w = tid >> 6;
  int lr = l & 15, lg = l >> 4;
  int wr = (w >> 1) * 64, wc = (w & 1) * 64;

  const unsigned short* gA = A + (mbase + w * 32 + (l >> 2)) * 512 +
                             (((l & 3) ^ ((l >> 3) & 3))) * 8;
  const unsigned short* gB = BT + (size_t)(nbase + w * 32 + (l >> 2)) * 512 +
                             (((l & 3) ^ ((l >> 3) & 3))) * 8;

  GLDS16(gA, smem + w * 1024);
  GLDS16(gA + 16 * 512, smem + w * 1024 + 512);
  GLDS16(gB, smem + 4096 + w * 1024);
  GLDS16(gB + 16 * 512, smem + 4096 + w * 1024 + 512);
  GLDS16(gA + 32, smem + 8192 + w * 1024);
  GLDS16(gA + 32 + 16 * 512, smem + 8192 + w * 1024 + 512);
  GLDS16(gB + 32, smem + 12288 + w * 1024);
  GLDS16(gB + 32 + 16 * 512, smem + 12288 + w * 1024 + 512);

  f32x4 acc[4][4] = {};
#pragma unroll 1
  for (int t = 0; t < 16; t += 2) {
    KSTEP(t, 0);
    KSTEP(t + 1, 8192);
  }

#pragma unroll
  for (int m = 0; m < 4; ++m) {
#pragma unroll
    for (int n = 0; n < 4; ++n) {
#pragma unroll
      for (int reg = 0; reg < 4; ++reg) {
        size_t row = mbase + wr + m * 16 + lg * 4 + reg;
        int col = nbase + wc + n * 16 + lr;
        Out[row * 512 + col] = acc[m][n][reg] + bias[col];
      }
    }
  }
}

// ---------------------------------------------------------------------------
// Workspace layout (bytes)
// ---------------------------------------------------------------------------
static const size_t OFF_Q   = 0;                         // 8*4096*512*2 = 33554432
static const size_t OFF_KP  = 33554432;                  // 8*8*80*64*2  = 655360
static const size_t OFF_VT  = OFF_KP + 655360;           // 8*8*64*96*2  = 786432
static const size_t OFF_WQT = OFF_VT + 786432;           // 512*512*2
static const size_t OFF_WKT = OFF_WQT + 524288;          // 512*768*2
static const size_t OFF_WVT = OFF_WKT + 786432;          // 512*768*2
static const size_t OFF_WOT = OFF_WVT + 786432;          // 512*512*2
static const size_t WS_NEEDED = OFF_WOT + 524288;        // 37617664

extern "C" void kernel_launch(void* const* d_in, const int* in_sizes, int n_in,
                              void* d_out, int out_size, void* d_ws, size_t ws_size,
                              hipStream_t stream) {
  (void)in_sizes; (void)n_in; (void)out_size;
  if (ws_size < WS_NEEDED) return;

  const float* latent  = (const float*)d_in[0];
  const float* context = (const float*)d_in[1];
  const float* wq = (const float*)d_in[2];
  const float* bq = (const float*)d_in[3];
  const float* wk = (const float*)d_in[4];
  const float* bk = (const float*)d_in[5];
  const float* wv = (const float*)d_in[6];
  const float* bv = (const float*)d_in[7];
  const float* wo = (const float*)d_in[8];
  const float* bo = (const float*)d_in[9];
  float* out = (float*)d_out;

  char* ws = (char*)d_ws;
  unsigned short* wsQ = (unsigned short*)(ws + OFF_Q);   // attn output (bf16)
  unsigned short* Kp  = (unsigned short*)(ws + OFF_KP);
  unsigned short* Vt  = (unsigned short*)(ws + OFF_VT);
  unsigned short* wqT = (unsigned short*)(ws + OFF_WQT);
  unsigned short* wkT = (unsigned short*)(ws + OFF_WKT);
  unsigned short* wvT = (unsigned short*)(ws + OFF_WVT);
  unsigned short* woT = (unsigned short*)(ws + OFF_WOT);

  // latent bf16 parked in d_out (first 33.5MB); consumed by qproj, then
  // d_out fully rewritten by the final GEMM.
  unsigned short* latBF = (unsigned short*)d_out;

  wtrans_all_kernel<<<1280, 256, 0, stream>>>(wq, wk, wv, wo,
                                              wqT, wkT, wvT, woT);
  hipMemsetAsync(ws + OFF_KP, 0, 655360 + 786432, stream);
  kv_proj_kernel<<<160, 256, 0, stream>>>(context, wkT, wvT, bk, bv, Kp, Vt);
  cvt_bf16_kernel<<<8192, 256, 0, stream>>>(latent, (unsigned int*)latBF);
  qproj_attn_kernel<<<2048, 256, 0, stream>>>(latBF, wqT, bq, Kp, Vt, wsQ);
  gemm512_glds_kernel<<<1024, 256, 0, stream>>>(wsQ, woT, bo, out);
}

// Round 17
// 113.957 us; speedup vs baseline: 1.2385x; 1.2385x over previous
//
#include <hip/hip_runtime.h>

// CrossAttention on MI355X (gfx950), round 17.
// B=8 SQ=4096 SKV=77 DE=512 DC=768 H=8 DH=64.
// R17 (base = R13, 115.5us; R16 geometry reverted): (1) attn-tail O-stores
// staged through wave-private LDS -> 2x global_store_dwordx4 per rg instead
// of 16 scalar 2B stores; (2) Kp/Vt zeroing folded into wtrans (memset
// dispatch gone; zero path has no MFMA so no R14 regalloc hazard).
// qproj GEMM = fp32-A dbuf + single-B + counted vmcnt(4), 40960B LDS,
// 4 blocks/CU (proven R13). ogemm unchanged (R12).

typedef __attribute__((ext_vector_type(8))) __bf16 bf16x8;
typedef __attribute__((ext_vector_type(4))) float f32x4;

#define DEVI static __device__ __forceinline__

typedef __attribute__((address_space(3))) void lds_void_t;
typedef const __attribute__((address_space(1))) void gbl_void_t;
#define GLDS16(gsrc, ldst) \
  __builtin_amdgcn_global_load_lds((gbl_void_t*)(gsrc), (lds_void_t*)(ldst), 16, 0, 0)

DEVI unsigned short f2bf(float f) {
  unsigned int u = __float_as_uint(f);
  u += 0x7FFFu + ((u >> 16) & 1u);   // round-to-nearest-even
  return (unsigned short)(u >> 16);
}

DEVI unsigned int cvt_pk_bf16(float lo, float hi) {
  unsigned int r;
  asm("v_cvt_pk_bf16_f32 %0, %1, %2" : "=v"(r) : "v"(lo), "v"(hi));
  return r;
}

DEVI bf16x8 cvt8(float4 a, float4 b) {
  uint4 u;
  u.x = cvt_pk_bf16(a.x, a.y);
  u.y = cvt_pk_bf16(a.z, a.w);
  u.z = cvt_pk_bf16(b.x, b.y);
  u.w = cvt_pk_bf16(b.z, b.w);
  return *(bf16x8*)&u;
}

// ---------------------------------------------------------------------------
// Weight transposes (blocks 0..1279) + Kp/Vt zero-fill (blocks 1280..1631).
// Zero path: 352 blocks x 256 threads x 16B = 1441792 B (Kp 655360 + Vt
// 786432). No MFMA anywhere in this kernel -> no regalloc hazard.
// ---------------------------------------------------------------------------
__global__ __launch_bounds__(256) void wtrans_all_kernel(
    const float* __restrict__ wq, const float* __restrict__ wk,
    const float* __restrict__ wv, const float* __restrict__ wo,
    unsigned short* __restrict__ wqT, unsigned short* __restrict__ wkT,
    unsigned short* __restrict__ wvT, unsigned short* __restrict__ woT,
    uint4* __restrict__ zbuf) {
  __shared__ float tile[32][33];
  int bid = blockIdx.x;
  int tid = threadIdx.x;
  if (bid >= 1280) {  // ---- zero-fill Kp+Vt ----
    uint4 z = {0u, 0u, 0u, 0u};
    zbuf[(size_t)(bid - 1280) * 256 + tid] = z;
    return;
  }
  const float* in;
  unsigned short* out;
  int K, r;
  if (bid < 256)       { in = wq; out = wqT; K = 512; r = bid; }
  else if (bid < 640)  { in = wk; out = wkT; K = 768; r = bid - 256; }
  else if (bid < 1024) { in = wv; out = wvT; K = 768; r = bid - 640; }
  else                 { in = wo; out = woT; K = 512; r = bid - 1024; }
  int n0 = (r & 15) * 32, k0 = (r >> 4) * 32;
  int tx = tid & 31, ty = tid >> 5;
#pragma unroll
  for (int j = 0; j < 4; ++j)
    tile[ty * 4 + j][tx] = in[(size_t)(k0 + ty * 4 + j) * 512 + n0 + tx];
  __syncthreads();
#pragma unroll
  for (int j = 0; j < 4; ++j)
    out[(size_t)(n0 + ty * 4 + j) * K + k0 + tx] = f2bf(tile[tx][ty * 4 + j]);
}

// ---------------------------------------------------------------------------
// K/V projection (standalone, proven)
// ---------------------------------------------------------------------------
__global__ __launch_bounds__(256) void kv_proj_kernel(const float* __restrict__ ctx,
                                                      const unsigned short* __restrict__ wkT,
                                                      const unsigned short* __restrict__ wvT,
                                                      const float* __restrict__ bk,
                                                      const float* __restrict__ bv,
                                                      unsigned short* __restrict__ Kp,
                                                      unsigned short* __restrict__ Vt) {
  __shared__ __align__(16) unsigned short As[64][40];
  __shared__ __align__(16) unsigned short Bs[64][40];
  int bid = blockIdx.x;
  int sel = bid / 80;
  int rem = bid % 80;
  int mt = rem / 8, nt = rem % 8;
  const unsigned short* wT = sel ? wvT : wkT;
  const float* bias = sel ? bv : bk;
  int tid = threadIdx.x;
  int l = tid & 63, w = tid >> 6;
  int lr = l & 15, lg = l >> 4;

  f32x4 acc[4] = {};
  for (int k0 = 0; k0 < 768; k0 += 32) {
#pragma unroll
    for (int it = 0; it < 2; ++it) {
      int idx4 = it * 256 + tid;
      int r = idx4 >> 3, q4 = idx4 & 7;
      int m = mt * 64 + r;
      float4 v = {0.f, 0.f, 0.f, 0.f};
      if (m < 616) v = *(const float4*)(ctx + (size_t)m * 768 + k0 + q4 * 4);
      ushort4 o;
      o.x = f2bf(v.x); o.y = f2bf(v.y); o.z = f2bf(v.z); o.w = f2bf(v.w);
      *(ushort4*)&As[r][q4 * 4] = o;
    }
    {
      int c = tid >> 2, q8 = tid & 3;
      *(uint4*)&Bs[c][q8 * 8] =
          *(const uint4*)(wT + (size_t)(nt * 64 + c) * 768 + k0 + q8 * 8);
    }
    __syncthreads();
    bf16x8 a = *(const bf16x8*)&As[w * 16 + lr][lg * 8];
#pragma unroll
    for (int n = 0; n < 4; ++n) {
      bf16x8 bb = *(const bf16x8*)&Bs[n * 16 + lr][lg * 8];
      acc[n] = __builtin_amdgcn_mfma_f32_16x16x32_bf16(a, bb, acc[n], 0, 0, 0);
    }
    __syncthreads();
  }
#pragma unroll
  for (int n = 0; n < 4; ++n) {
#pragma unroll
    for (int reg = 0; reg < 4; ++reg) {
      int m = mt * 64 + w * 16 + lg * 4 + reg;
      if (m < 616) {
        int bI = m / 77, s = m % 77;
        int col = nt * 64 + n * 16 + lr;
        int h = col >> 6, d = col & 63;
        float v = acc[n][reg] + bias[col];
        if (sel == 0)
          Kp[(((size_t)(bI * 8 + h)) * 80 + s) * 64 + d] = f2bf(v);
        else
          Vt[(((size_t)(bI * 8 + h)) * 64 + d) * 96 + s] = f2bf(v);
      }
    }
  }
}

// ---------------------------------------------------------------------------
// qproj K-step: A fp32 dbuf (AO = 0 / 8192 u16), B bf16 SINGLE buffer @16384.
// Per step: B(t+1)x2 first, then A(t+2)x4 -> entry vmcnt(4) completes exactly
// A(t)x4 + B(t)x2. (proven R13)
// ---------------------------------------------------------------------------
#define QSTEP(t, AO)                                                          \
  {                                                                           \
    if ((t) < 15)                                                             \
      asm volatile("s_waitcnt vmcnt(4)" ::: "memory");                        \
    else                                                                      \
      asm volatile("s_waitcnt vmcnt(0)" ::: "memory");                        \
    __builtin_amdgcn_s_barrier();                                             \
    __builtin_amdgcn_sched_barrier(0);                                        \
    const float* Af = (const float*)(smem + (AO));                            \
    const unsigned short* Bf = smem + 16384;                                  \
    const int swA = lr & 7;                                                   \
    const int swB = (lr >> 1) & 3;                                            \
    float4 ax[4], ay[4];                                                      \
    bf16x8 bv8[4];                                                            \
    _Pragma("unroll") for (int m = 0; m < 4; ++m) {                           \
      ax[m] = *(const float4*)&Af[(wr + m * 16 + lr) * 32 +                   \
                                  ((2 * lg) ^ swA) * 4];                      \
      ay[m] = *(const float4*)&Af[(wr + m * 16 + lr) * 32 +                   \
                                  ((2 * lg + 1) ^ swA) * 4];                  \
    }                                                                         \
    _Pragma("unroll") for (int n = 0; n < 4; ++n)                             \
        bv8[n] = *(const bf16x8*)&Bf[(wc + n * 16 + lr) * 32 +                \
                                     (lg ^ swB) * 8];                         \
    asm volatile("s_waitcnt lgkmcnt(0)" ::: "memory");                        \
    __builtin_amdgcn_sched_barrier(0);                                        \
    __builtin_amdgcn_s_barrier();                                             \
    if ((t) <= 14) {                                                          \
      int nk1 = ((t) + 1) * 32;                                               \
      GLDS16(gB + nk1, smem + 16384 + w * 1024);                              \
      GLDS16(gB + nk1 + 16 * 512, smem + 16384 + w * 1024 + 512);             \
    }                                                                         \
    if ((t) <= 13) {                                                          \
      int nk2 = ((t) + 2) * 32;                                               \
      _Pragma("unroll") for (int i = 0; i < 4; ++i)                           \
          GLDS16(gA32 + nk2 + i * 4096, smem + (AO) + w * 2048 + i * 512);    \
    }                                                                         \
    bf16x8 af[4];                                                             \
    _Pragma("unroll") for (int m = 0; m < 4; ++m) af[m] = cvt8(ax[m], ay[m]); \
    _Pragma("unroll") for (int m = 0; m < 4; ++m)                             \
        _Pragma("unroll") for (int n = 0; n < 4; ++n)                         \
            acc[m][n] = __builtin_amdgcn_mfma_f32_16x16x32_bf16(              \
                af[m], bv8[n], acc[m][n], 0, 0, 0);                           \
  }

// ---------------------------------------------------------------------------
// FUSED Q-proj + attention (R13 base + LDS-staged O-stores).
// LDS: A0@0 | A1@8192 | B@16384 = 40960 B -> 4 blocks/CU.
// ---------------------------------------------------------------------------
__global__ __launch_bounds__(256, 4) void qproj_attn_kernel(
    const float* __restrict__ A32, const unsigned short* __restrict__ BT,
    const float* __restrict__ bias, const unsigned short* __restrict__ Kp,
    const unsigned short* __restrict__ Vt, unsigned short* __restrict__ Oq) {
  __shared__ __align__(16) unsigned short smem[20480];  // 40960 B

  int bid = ((blockIdx.x & 7) << 7) | (blockIdx.x >> 3);  // XCD swizzle
  size_t mbase = (size_t)(bid >> 2) * 128;
  int nbase = (bid & 3) * 128;
  int tid = threadIdx.x;
  int l = tid & 63, w = tid >> 6;
  int lr = l & 15, lg = l >> 4;
  int wr = (w >> 1) * 64, wc = (w & 1) * 64;

  const float* gA32 =
      A32 + (mbase + w * 32 + (l >> 3)) * 512 + (((l & 7) ^ (l >> 3))) * 4;
  const unsigned short* gB = BT + (size_t)(nbase + w * 32 + (l >> 2)) * 512 +
                             (((l & 3) ^ ((l >> 3) & 3))) * 8;

  // prologue: A(0)x4, B(0)x2, A(1)x4
#pragma unroll
  for (int i = 0; i < 4; ++i) GLDS16(gA32 + i * 4096, smem + w * 2048 + i * 512);
  GLDS16(gB, smem + 16384 + w * 1024);
  GLDS16(gB + 16 * 512, smem + 16384 + w * 1024 + 512);
#pragma unroll
  for (int i = 0; i < 4; ++i)
    GLDS16(gA32 + 32 + i * 4096, smem + 8192 + w * 2048 + i * 512);

  f32x4 acc[4][4] = {};
#pragma unroll 1
  for (int t = 0; t < 16; t += 2) {
    QSTEP(t, 0);
    QSTEP(t + 1, 8192);
  }

  // ---- epilogue: Q quadrant -> wave-private LDS (transpose), +bias ----
  unsigned short* Qme = smem + w * (64 * 72);
  float bb[4];
#pragma unroll
  for (int n = 0; n < 4; ++n) bb[n] = bias[nbase + wc + n * 16 + lr];
#pragma unroll
  for (int m = 0; m < 4; ++m)
#pragma unroll
    for (int n = 0; n < 4; ++n)
#pragma unroll
      for (int reg = 0; reg < 4; ++reg)
        Qme[(m * 16 + lg * 4 + reg) * 72 + n * 16 + lr] = f2bf(acc[m][n][reg] + bb[n]);

  bf16x8 qf[4][2];
#pragma unroll
  for (int rg = 0; rg < 4; ++rg) {
    qf[rg][0] = *(const bf16x8*)&Qme[(rg * 16 + lr) * 72 + lg * 8];
    qf[rg][1] = *(const bf16x8*)&Qme[(rg * 16 + lr) * 72 + 32 + lg * 8];
  }

  // wave-private P (16x104) at Qme+0; O staging (16x72) at Qme+1664.
  unsigned short* Pme = Qme;
  unsigned short* Ome = Qme + 1664;
  for (int z = l; z < 256; z += 64) Pme[(z >> 4) * 104 + 80 + (z & 15)] = 0;

  // ---- wave-local attention: 64 q-rows x head h ----
  int b = (int)(mbase >> 12);
  int h = (bid & 3) * 2 + (w & 1);
  const unsigned short* Kph = Kp + (size_t)(b * 8 + h) * (80 * 64);
  const unsigned short* Vth = Vt + (size_t)(b * 8 + h) * (64 * 96);

  const float C = 0.125f * 1.44269504088896f;  // 1/sqrt(64) * log2(e)

  auto QK = [&](int rg, f32x4* s) {
#pragma unroll
    for (int t = 0; t < 5; ++t) {
      const unsigned short* kr = Kph + (t * 16 + lr) * 64 + lg * 8;
      bf16x8 k0 = *(const bf16x8*)kr;
      bf16x8 k1 = *(const bf16x8*)(kr + 32);
      s[t] = __builtin_amdgcn_mfma_f32_16x16x32_bf16(qf[rg][0], k0, s[t], 0, 0, 0);
      s[t] = __builtin_amdgcn_mfma_f32_16x16x32_bf16(qf[rg][1], k1, s[t], 0, 0, 0);
    }
    if (lr >= 13) {  // cols 64+lr >= 77 are pad
      s[4][0] = -1e30f; s[4][1] = -1e30f; s[4][2] = -1e30f; s[4][3] = -1e30f;
    }
  };

  f32x4 sc[5] = {};
  QK(0, sc);
#pragma unroll
  for (int rg = 0; rg < 4; ++rg) {
    float mx[4];
#pragma unroll
    for (int r = 0; r < 4; ++r)
      mx[r] = fmaxf(fmaxf(fmaxf(sc[0][r], sc[1][r]), fmaxf(sc[2][r], sc[3][r])), sc[4][r]);
#pragma unroll
    for (int d = 1; d < 16; d <<= 1)
#pragma unroll
      for (int r = 0; r < 4; ++r) mx[r] = fmaxf(mx[r], __shfl_xor(mx[r], d, 64));
    float p[5][4];
#pragma unroll
    for (int t = 0; t < 5; ++t)
#pragma unroll
      for (int r = 0; r < 4; ++r) p[t][r] = exp2f((sc[t][r] - mx[r]) * C);
#pragma unroll
    for (int t = 0; t < 5; ++t)
#pragma unroll
      for (int r = 0; r < 4; ++r)
        Pme[(lg * 4 + r) * 104 + t * 16 + lr] = f2bf(p[t][r]);

    float sm[4];
#pragma unroll
    for (int r = 0; r < 4; ++r)
      sm[r] = p[0][r] + p[1][r] + p[2][r] + p[3][r] + p[4][r];
#pragma unroll
    for (int d = 1; d < 16; d <<= 1)
#pragma unroll
      for (int r = 0; r < 4; ++r) sm[r] += __shfl_xor(sm[r], d, 64);
    float rs[4];
#pragma unroll
    for (int r = 0; r < 4; ++r) rs[r] = 1.0f / sm[r];

    f32x4 sn[5] = {};
    if (rg < 3) QK(rg + 1, sn);

    bf16x8 ap[3];
#pragma unroll
    for (int c = 0; c < 3; ++c) ap[c] = *(const bf16x8*)&Pme[lr * 104 + c * 32 + lg * 8];
#pragma unroll
    for (int ct = 0; ct < 4; ++ct) {
      f32x4 o = {};
#pragma unroll
      for (int c = 0; c < 3; ++c) {
        bf16x8 vv = *(const bf16x8*)(Vth + (size_t)(ct * 16 + lr) * 96 + c * 32 + lg * 8);
        o = __builtin_amdgcn_mfma_f32_16x16x32_bf16(ap[c], vv, o, 0, 0, 0);
      }
#pragma unroll
      for (int reg = 0; reg < 4; ++reg)
        Ome[(lg * 4 + reg) * 72 + ct * 16 + lr] = f2bf(o[reg] * rs[reg]);
    }
    // coalesced write-back of the 16x64 chunk (wave-synchronous; compiler
    // orders the ds_read after the ds_writes via lgkmcnt)
    {
      size_t rowbase = mbase + wr + rg * 16;
      int r8 = l >> 3, c8 = (l & 7) * 8;
      uint4 v0 = *(const uint4*)&Ome[r8 * 72 + c8];
      uint4 v1 = *(const uint4*)&Ome[(r8 + 8) * 72 + c8];
      *(uint4*)&Oq[(rowbase + r8) * 512 + nbase + wc + c8] = v0;
      *(uint4*)&Oq[(rowbase + r8 + 8) * 512 + nbase + wc + c8] = v1;
    }
#pragma unroll
    for (int t = 0; t < 5; ++t) sc[t] = sn[t];
  }
}

// ---------------------------------------------------------------------------
// O-proj K-step (bf16 A+B, both slot^=((row>>1)&3)); unchanged R12.
// ---------------------------------------------------------------------------
#define KSTEP(t, boff)                                                        \
  {                                                                           \
    if ((t) < 15)                                                             \
      asm volatile("s_waitcnt vmcnt(4)" ::: "memory");                        \
    else                                                                      \
      asm volatile("s_waitcnt vmcnt(0)" ::: "memory");                        \
    __builtin_amdgcn_s_barrier();                                             \
    __builtin_amdgcn_sched_barrier(0);                                        \
    const unsigned short* bufA = smem + (boff);                               \
    const unsigned short* bufB = bufA + 4096;                                 \
    const int swB = (lr >> 1) & 3;                                            \
    bf16x8 af[4], bv8[4];                                                     \
    _Pragma("unroll") for (int m = 0; m < 4; ++m)                             \
        af[m] = *(const bf16x8*)&bufA[(wr + m * 16 + lr) * 32 +               \
                                      (lg ^ swB) * 8];                        \
    _Pragma("unroll") for (int n = 0; n < 4; ++n)                             \
        bv8[n] = *(const bf16x8*)&bufB[(wc + n * 16 + lr) * 32 +              \
                                       (lg ^ swB) * 8];                       \
    asm volatile("s_waitcnt lgkmcnt(0)" ::: "memory");                        \
    __builtin_amdgcn_sched_barrier(0);                                        \
    __builtin_amdgcn_s_barrier();                                             \
    if ((t) <= 13) {                                                          \
      int nk = ((t) + 2) * 32;                                                \
      GLDS16(gA + nk, smem + (boff) + w * 1024);                              \
      GLDS16(gA + nk + 16 * 512, smem + (boff) + w * 1024 + 512);             \
      GLDS16(gB + nk, smem + (boff) + 4096 + w * 1024);                       \
      GLDS16(gB + nk + 16 * 512, smem + (boff) + 4096 + w * 1024 + 512);      \
    }                                                                         \
    _Pragma("unroll") for (int m = 0; m < 4; ++m)                             \
        _Pragma("unroll") for (int n = 0; n < 4; ++n)                         \
            acc[m][n] = __builtin_amdgcn_mfma_f32_16x16x32_bf16(              \
                af[m], bv8[n], acc[m][n], 0, 0, 0);                           \
  }

__global__ __launch_bounds__(256) void gemm512_glds_kernel(
    const unsigned short* __restrict__ A, const unsigned short* __restrict__ BT,
    const float* __restrict__ bias, float* __restrict__ Out) {
  __shared__ __align__(16) unsigned short smem[16384];  // 32 KB
  int bid = ((blockIdx.x & 7) << 7) | (blockIdx.x >> 3);  // XCD swizzle
  size_t mbase = (size_t)(bid >> 2) * 128;
  int nbase = (bid & 3) * 128;
  int tid = threadIdx.x;
  int l = tid & 63, w = tid >> 6;
  int lr = l & 15, lg = l >> 4;
  int wr = (w >> 1) * 64, wc = (w & 1) * 64;

  const unsigned short* gA = A + (mbase + w * 32 + (l >> 2)) * 512 +
                             (((l & 3) ^ ((l >> 3) & 3))) * 8;
  const unsigned short* gB = BT + (size_t)(nbase + w * 32 + (l >> 2)) * 512 +
                             (((l & 3) ^ ((l >> 3) & 3))) * 8;

  GLDS16(gA, smem + w * 1024);
  GLDS16(gA + 16 * 512, smem + w * 1024 + 512);
  GLDS16(gB, smem + 4096 + w * 1024);
  GLDS16(gB + 16 * 512, smem + 4096 + w * 1024 + 512);
  GLDS16(gA + 32, smem + 8192 + w * 1024);
  GLDS16(gA + 32 + 16 * 512, smem + 8192 + w * 1024 + 512);
  GLDS16(gB + 32, smem + 12288 + w * 1024);
  GLDS16(gB + 32 + 16 * 512, smem + 12288 + w * 1024 + 512);

  f32x4 acc[4][4] = {};
#pragma unroll 1
  for (int t = 0; t < 16; t += 2) {
    KSTEP(t, 0);
    KSTEP(t + 1, 8192);
  }

#pragma unroll
  for (int m = 0; m < 4; ++m) {
#pragma unroll
    for (int n = 0; n < 4; ++n) {
#pragma unroll
      for (int reg = 0; reg < 4; ++reg) {
        size_t row = mbase + wr + m * 16 + lg * 4 + reg;
        int col = nbase + wc + n * 16 + lr;
        Out[row * 512 + col] = acc[m][n][reg] + bias[col];
      }
    }
  }
}

// ---------------------------------------------------------------------------
// Workspace layout (bytes)
// ---------------------------------------------------------------------------
static const size_t OFF_Q   = 0;                         // 8*4096*512*2 = 33554432
static const size_t OFF_KP  = 33554432;                  // 8*8*80*64*2  = 655360
static const size_t OFF_VT  = OFF_KP + 655360;           // 8*8*64*96*2  = 786432
static const size_t OFF_WQT = OFF_VT + 786432;           // 512*512*2
static const size_t OFF_WKT = OFF_WQT + 524288;          // 512*768*2
static const size_t OFF_WVT = OFF_WKT + 786432;          // 512*768*2
static const size_t OFF_WOT = OFF_WVT + 786432;          // 512*512*2
static const size_t WS_NEEDED = OFF_WOT + 524288;        // 37617664

extern "C" void kernel_launch(void* const* d_in, const int* in_sizes, int n_in,
                              void* d_out, int out_size, void* d_ws, size_t ws_size,
                              hipStream_t stream) {
  (void)in_sizes; (void)n_in; (void)out_size;
  if (ws_size < WS_NEEDED) return;

  const float* latent  = (const float*)d_in[0];
  const float* context = (const float*)d_in[1];
  const float* wq = (const float*)d_in[2];
  const float* bq = (const float*)d_in[3];
  const float* wk = (const float*)d_in[4];
  const float* bk = (const float*)d_in[5];
  const float* wv = (const float*)d_in[6];
  const float* bv = (const float*)d_in[7];
  const float* wo = (const float*)d_in[8];
  const float* bo = (const float*)d_in[9];
  float* out = (float*)d_out;

  char* ws = (char*)d_ws;
  unsigned short* wsQ = (unsigned short*)(ws + OFF_Q);   // attn output (bf16)
  unsigned short* Kp  = (unsigned short*)(ws + OFF_KP);
  unsigned short* Vt  = (unsigned short*)(ws + OFF_VT);
  unsigned short* wqT = (unsigned short*)(ws + OFF_WQT);
  unsigned short* wkT = (unsigned short*)(ws + OFF_WKT);
  unsigned short* wvT = (unsigned short*)(ws + OFF_WVT);
  unsigned short* woT = (unsigned short*)(ws + OFF_WOT);

  // wtrans + Kp/Vt zero-fill in one launch (zero region = 1441792 B = 352
  // blocks x 4096 B).
  wtrans_all_kernel<<<1280 + 352, 256, 0, stream>>>(
      wq, wk, wv, wo, wqT, wkT, wvT, woT, (uint4*)(ws + OFF_KP));
  kv_proj_kernel<<<160, 256, 0, stream>>>(context, wkT, wvT, bk, bv, Kp, Vt);
  qproj_attn_kernel<<<1024, 256, 0, stream>>>(latent, wqT, bq, Kp, Vt, wsQ);
  gemm512_glds_kernel<<<1024, 256, 0, stream>>>(wsQ, woT, bo, out);
}

// Round 18
// 109.708 us; speedup vs baseline: 1.2865x; 1.0387x over previous
//
#include <hip/hip_runtime.h>

// CrossAttention on MI355X (gfx950), round 18.
// B=8 SQ=4096 SKV=77 DE=512 DC=768 H=8 DH=64.
// R18 (base = R17, 114.0us): swapped-QK attention tail (T12 adapted to
// 16x16): compute mfma(K,Q) so each lane holds all 20 scores of ONE q-row
// (q = lr). Softmax = per-lane scalar + 2 shfl_xor; normalization folded
// into P before cvt_pk packing; P redistributed to PV A-frags via 20
// __shfl + selects -- NO LDS roundtrip. O-stores back to direct scalar
// (R17's LDS staging was mildly negative). GEMM structure unchanged (R13:
// fp32-A dbuf + single-B + counted vmcnt); ogemm/kv/wtrans+zero unchanged.

typedef __attribute__((ext_vector_type(8))) __bf16 bf16x8;
typedef __attribute__((ext_vector_type(4))) float f32x4;

#define DEVI static __device__ __forceinline__

typedef __attribute__((address_space(3))) void lds_void_t;
typedef const __attribute__((address_space(1))) void gbl_void_t;
#define GLDS16(gsrc, ldst) \
  __builtin_amdgcn_global_load_lds((gbl_void_t*)(gsrc), (lds_void_t*)(ldst), 16, 0, 0)

DEVI unsigned short f2bf(float f) {
  unsigned int u = __float_as_uint(f);
  u += 0x7FFFu + ((u >> 16) & 1u);   // round-to-nearest-even
  return (unsigned short)(u >> 16);
}

DEVI unsigned int cvt_pk_bf16(float lo, float hi) {
  unsigned int r;
  asm("v_cvt_pk_bf16_f32 %0, %1, %2" : "=v"(r) : "v"(lo), "v"(hi));
  return r;
}

DEVI bf16x8 cvt8(float4 a, float4 b) {
  uint4 u;
  u.x = cvt_pk_bf16(a.x, a.y);
  u.y = cvt_pk_bf16(a.z, a.w);
  u.z = cvt_pk_bf16(b.x, b.y);
  u.w = cvt_pk_bf16(b.z, b.w);
  return *(bf16x8*)&u;
}

// ---------------------------------------------------------------------------
// Weight transposes (blocks 0..1279) + Kp/Vt zero-fill (blocks 1280..1631).
// ---------------------------------------------------------------------------
__global__ __launch_bounds__(256) void wtrans_all_kernel(
    const float* __restrict__ wq, const float* __restrict__ wk,
    const float* __restrict__ wv, const float* __restrict__ wo,
    unsigned short* __restrict__ wqT, unsigned short* __restrict__ wkT,
    unsigned short* __restrict__ wvT, unsigned short* __restrict__ woT,
    uint4* __restrict__ zbuf) {
  __shared__ float tile[32][33];
  int bid = blockIdx.x;
  int tid = threadIdx.x;
  if (bid >= 1280) {  // ---- zero-fill Kp+Vt ----
    uint4 z = {0u, 0u, 0u, 0u};
    zbuf[(size_t)(bid - 1280) * 256 + tid] = z;
    return;
  }
  const float* in;
  unsigned short* out;
  int K, r;
  if (bid < 256)       { in = wq; out = wqT; K = 512; r = bid; }
  else if (bid < 640)  { in = wk; out = wkT; K = 768; r = bid - 256; }
  else if (bid < 1024) { in = wv; out = wvT; K = 768; r = bid - 640; }
  else                 { in = wo; out = woT; K = 512; r = bid - 1024; }
  int n0 = (r & 15) * 32, k0 = (r >> 4) * 32;
  int tx = tid & 31, ty = tid >> 5;
#pragma unroll
  for (int j = 0; j < 4; ++j)
    tile[ty * 4 + j][tx] = in[(size_t)(k0 + ty * 4 + j) * 512 + n0 + tx];
  __syncthreads();
#pragma unroll
  for (int j = 0; j < 4; ++j)
    out[(size_t)(n0 + ty * 4 + j) * K + k0 + tx] = f2bf(tile[tx][ty * 4 + j]);
}

// ---------------------------------------------------------------------------
// K/V projection (standalone, proven)
// ---------------------------------------------------------------------------
__global__ __launch_bounds__(256) void kv_proj_kernel(const float* __restrict__ ctx,
                                                      const unsigned short* __restrict__ wkT,
                                                      const unsigned short* __restrict__ wvT,
                                                      const float* __restrict__ bk,
                                                      const float* __restrict__ bv,
                                                      unsigned short* __restrict__ Kp,
                                                      unsigned short* __restrict__ Vt) {
  __shared__ __align__(16) unsigned short As[64][40];
  __shared__ __align__(16) unsigned short Bs[64][40];
  int bid = blockIdx.x;
  int sel = bid / 80;
  int rem = bid % 80;
  int mt = rem / 8, nt = rem % 8;
  const unsigned short* wT = sel ? wvT : wkT;
  const float* bias = sel ? bv : bk;
  int tid = threadIdx.x;
  int l = tid & 63, w = tid >> 6;
  int lr = l & 15, lg = l >> 4;

  f32x4 acc[4] = {};
  for (int k0 = 0; k0 < 768; k0 += 32) {
#pragma unroll
    for (int it = 0; it < 2; ++it) {
      int idx4 = it * 256 + tid;
      int r = idx4 >> 3, q4 = idx4 & 7;
      int m = mt * 64 + r;
      float4 v = {0.f, 0.f, 0.f, 0.f};
      if (m < 616) v = *(const float4*)(ctx + (size_t)m * 768 + k0 + q4 * 4);
      ushort4 o;
      o.x = f2bf(v.x); o.y = f2bf(v.y); o.z = f2bf(v.z); o.w = f2bf(v.w);
      *(ushort4*)&As[r][q4 * 4] = o;
    }
    {
      int c = tid >> 2, q8 = tid & 3;
      *(uint4*)&Bs[c][q8 * 8] =
          *(const uint4*)(wT + (size_t)(nt * 64 + c) * 768 + k0 + q8 * 8);
    }
    __syncthreads();
    bf16x8 a = *(const bf16x8*)&As[w * 16 + lr][lg * 8];
#pragma unroll
    for (int n = 0; n < 4; ++n) {
      bf16x8 bb = *(const bf16x8*)&Bs[n * 16 + lr][lg * 8];
      acc[n] = __builtin_amdgcn_mfma_f32_16x16x32_bf16(a, bb, acc[n], 0, 0, 0);
    }
    __syncthreads();
  }
#pragma unroll
  for (int n = 0; n < 4; ++n) {
#pragma unroll
    for (int reg = 0; reg < 4; ++reg) {
      int m = mt * 64 + w * 16 + lg * 4 + reg;
      if (m < 616) {
        int bI = m / 77, s = m % 77;
        int col = nt * 64 + n * 16 + lr;
        int h = col >> 6, d = col & 63;
        float v = acc[n][reg] + bias[col];
        if (sel == 0)
          Kp[(((size_t)(bI * 8 + h)) * 80 + s) * 64 + d] = f2bf(v);
        else
          Vt[(((size_t)(bI * 8 + h)) * 64 + d) * 96 + s] = f2bf(v);
      }
    }
  }
}

// ---------------------------------------------------------------------------
// qproj K-step: A fp32 dbuf (AO = 0 / 8192 u16), B bf16 SINGLE buffer @16384.
// (proven R13)
// ---------------------------------------------------------------------------
#define QSTEP(t, AO)                                                          \
  {                                                                           \
    if ((t) < 15)                                                             \
      asm volatile("s_waitcnt vmcnt(4)" ::: "memory");                        \
    else                                                                      \
      asm volatile("s_waitcnt vmcnt(0)" ::: "memory");                        \
    __builtin_amdgcn_s_barrier();                                             \
    __builtin_amdgcn_sched_barrier(0);                                        \
    const float* Af = (const float*)(smem + (AO));                            \
    const unsigned short* Bf = smem + 16384;                                  \
    const int swA = lr & 7;                                                   \
    const int swB = (lr >> 1) & 3;                                            \
    float4 ax[4], ay[4];                                                      \
    bf16x8 bv8[4];                                                            \
    _Pragma("unroll") for (int m = 0; m < 4; ++m) {                           \
      ax[m] = *(const float4*)&Af[(wr + m * 16 + lr) * 32 +                   \
                                  ((2 * lg) ^ swA) * 4];                      \
      ay[m] = *(const float4*)&Af[(wr + m * 16 + lr) * 32 +                   \
                                  ((2 * lg + 1) ^ swA) * 4];                  \
    }                                                                         \
    _Pragma("unroll") for (int n = 0; n < 4; ++n)                             \
        bv8[n] = *(const bf16x8*)&Bf[(wc + n * 16 + lr) * 32 +                \
                                     (lg ^ swB) * 8];                         \
    asm volatile("s_waitcnt lgkmcnt(0)" ::: "memory");                        \
    __builtin_amdgcn_sched_barrier(0);                                        \
    __builtin_amdgcn_s_barrier();                                             \
    if ((t) <= 14) {                                                          \
      int nk1 = ((t) + 1) * 32;                                               \
      GLDS16(gB + nk1, smem + 16384 + w * 1024);                              \
      GLDS16(gB + nk1 + 16 * 512, smem + 16384 + w * 1024 + 512);             \
    }                                                                         \
    if ((t) <= 13) {                                                          \
      int nk2 = ((t) + 2) * 32;                                               \
      _Pragma("unroll") for (int i = 0; i < 4; ++i)                           \
          GLDS16(gA32 + nk2 + i * 4096, smem + (AO) + w * 2048 + i * 512);    \
    }                                                                         \
    bf16x8 af[4];                                                             \
    _Pragma("unroll") for (int m = 0; m < 4; ++m) af[m] = cvt8(ax[m], ay[m]); \
    _Pragma("unroll") for (int m = 0; m < 4; ++m)                             \
        _Pragma("unroll") for (int n = 0; n < 4; ++n)                         \
            acc[m][n] = __builtin_amdgcn_mfma_f32_16x16x32_bf16(              \
                af[m], bv8[n], acc[m][n], 0, 0, 0);                           \
  }

// ---------------------------------------------------------------------------
// FUSED Q-proj + attention with swapped-QK in-register-P tail.
// LDS: A0@0 | A1@8192 | B@16384 = 40960 B -> 4 blocks/CU.
// ---------------------------------------------------------------------------
__global__ __launch_bounds__(256, 4) void qproj_attn_kernel(
    const float* __restrict__ A32, const unsigned short* __restrict__ BT,
    const float* __restrict__ bias, const unsigned short* __restrict__ Kp,
    const unsigned short* __restrict__ Vt, unsigned short* __restrict__ Oq) {
  __shared__ __align__(16) unsigned short smem[20480];  // 40960 B

  int bid = ((blockIdx.x & 7) << 7) | (blockIdx.x >> 3);  // XCD swizzle
  size_t mbase = (size_t)(bid >> 2) * 128;
  int nbase = (bid & 3) * 128;
  int tid = threadIdx.x;
  int l = tid & 63, w = tid >> 6;
  int lr = l & 15, lg = l >> 4;
  int wr = (w >> 1) * 64, wc = (w & 1) * 64;

  const float* gA32 =
      A32 + (mbase + w * 32 + (l >> 3)) * 512 + (((l & 7) ^ (l >> 3))) * 4;
  const unsigned short* gB = BT + (size_t)(nbase + w * 32 + (l >> 2)) * 512 +
                             (((l & 3) ^ ((l >> 3) & 3))) * 8;

  // prologue: A(0)x4, B(0)x2, A(1)x4
#pragma unroll
  for (int i = 0; i < 4; ++i) GLDS16(gA32 + i * 4096, smem + w * 2048 + i * 512);
  GLDS16(gB, smem + 16384 + w * 1024);
  GLDS16(gB + 16 * 512, smem + 16384 + w * 1024 + 512);
#pragma unroll
  for (int i = 0; i < 4; ++i)
    GLDS16(gA32 + 32 + i * 4096, smem + 8192 + w * 2048 + i * 512);

  f32x4 acc[4][4] = {};
#pragma unroll 1
  for (int t = 0; t < 16; t += 2) {
    QSTEP(t, 0);
    QSTEP(t + 1, 8192);
  }

  // ---- epilogue: Q quadrant -> wave-private LDS (transpose), +bias ----
  unsigned short* Qme = smem + w * (64 * 72);
  float bb[4];
#pragma unroll
  for (int n = 0; n < 4; ++n) bb[n] = bias[nbase + wc + n * 16 + lr];
#pragma unroll
  for (int m = 0; m < 4; ++m)
#pragma unroll
    for (int n = 0; n < 4; ++n)
#pragma unroll
      for (int reg = 0; reg < 4; ++reg)
        Qme[(m * 16 + lg * 4 + reg) * 72 + n * 16 + lr] = f2bf(acc[m][n][reg] + bb[n]);

  bf16x8 qf[4][2];
#pragma unroll
  for (int rg = 0; rg < 4; ++rg) {
    qf[rg][0] = *(const bf16x8*)&Qme[(rg * 16 + lr) * 72 + lg * 8];
    qf[rg][1] = *(const bf16x8*)&Qme[(rg * 16 + lr) * 72 + 32 + lg * 8];
  }

  // ---- wave-local attention: 64 q-rows x head h; P stays in registers ----
  int b = (int)(mbase >> 12);
  int h = (bid & 3) * 2 + (w & 1);
  const unsigned short* Kph = Kp + (size_t)(b * 8 + h) * (80 * 64);
  const unsigned short* Vth = Vt + (size_t)(b * 8 + h) * (64 * 96);

  const float C = 0.125f * 1.44269504088896f;  // 1/sqrt(64) * log2(e)

  // swapped QK: A = K frag, B = Q frag -> lane (lr,lg) holds
  // S[k = t*16 + lg*4 + reg][q = lr].
  auto QK = [&](int rg, f32x4* s) {
#pragma unroll
    for (int t = 0; t < 5; ++t) {
      const unsigned short* kr = Kph + (t * 16 + lr) * 64 + lg * 8;
      bf16x8 k0 = *(const bf16x8*)kr;
      bf16x8 k1 = *(const bf16x8*)(kr + 32);
      s[t] = __builtin_amdgcn_mfma_f32_16x16x32_bf16(k0, qf[rg][0], s[t], 0, 0, 0);
      s[t] = __builtin_amdgcn_mfma_f32_16x16x32_bf16(k1, qf[rg][1], s[t], 0, 0, 0);
    }
  };

  const int srcLo = 32 * (lg & 1) + lr;  // source lanes for P redistribution
  const int srcHi = srcLo + 16;
  const int selHi = lg >> 1;

  f32x4 sc[5] = {};
  QK(0, sc);
#pragma unroll
  for (int rg = 0; rg < 4; ++rg) {
    // per-lane softmax over q-row lr (k rows 77..79 are zero-K => s=0; max
    // may include them (softmax is mx-invariant); they are zeroed post-exp).
    float mx = sc[0][0];
#pragma unroll
    for (int t = 0; t < 5; ++t)
#pragma unroll
      for (int r = 0; r < 4; ++r) mx = fmaxf(mx, sc[t][r]);
    mx = fmaxf(mx, __shfl_xor(mx, 16, 64));
    mx = fmaxf(mx, __shfl_xor(mx, 32, 64));
    float p[5][4];
#pragma unroll
    for (int t = 0; t < 5; ++t)
#pragma unroll
      for (int r = 0; r < 4; ++r) p[t][r] = exp2f((sc[t][r] - mx) * C);
    if (lg == 3) { p[4][1] = 0.f; p[4][2] = 0.f; p[4][3] = 0.f; }  // k>=77
    float sm = 0.f;
#pragma unroll
    for (int t = 0; t < 5; ++t)
#pragma unroll
      for (int r = 0; r < 4; ++r) sm += p[t][r];
    sm += __shfl_xor(sm, 16, 64);
    sm += __shfl_xor(sm, 32, 64);
    float rs = 1.0f / sm;
    // normalized P packed to bf16 pairs (k order: t*16 + lg*4 + {0..3})
    unsigned int pk[5][2];
#pragma unroll
    for (int t = 0; t < 5; ++t) {
      pk[t][0] = cvt_pk_bf16(p[t][0] * rs, p[t][1] * rs);
      pk[t][1] = cvt_pk_bf16(p[t][2] * rs, p[t][3] * rs);
    }

    // next QK (pure-reg MFMA + L1-hot K loads) overlaps the exchange/PV
    f32x4 sn[5] = {};
    if (rg < 3) QK(rg + 1, sn);

    // redistribute P to PV A-frags: dest (lr,lg) needs tile 2c+(lg>>1),
    // k-halves from lanes (lr, 2(lg&1)) and (lr, 2(lg&1)+1).
    bf16x8 ap[3];
#pragma unroll
    for (int c = 0; c < 3; ++c) {
      unsigned int a0 = __shfl((int)pk[2 * c][0], srcLo, 64);
      unsigned int a1 = __shfl((int)pk[2 * c][1], srcLo, 64);
      unsigned int a2 = __shfl((int)pk[2 * c][0], srcHi, 64);
      unsigned int a3 = __shfl((int)pk[2 * c][1], srcHi, 64);
      unsigned int b0 = 0, b1 = 0, b2 = 0, b3 = 0;
      if (c < 2) {
        b0 = __shfl((int)pk[2 * c + 1][0], srcLo, 64);
        b1 = __shfl((int)pk[2 * c + 1][1], srcLo, 64);
        b2 = __shfl((int)pk[2 * c + 1][0], srcHi, 64);
        b3 = __shfl((int)pk[2 * c + 1][1], srcHi, 64);
      }
      uint4 u;
      u.x = selHi ? b0 : a0;
      u.y = selHi ? b1 : a1;
      u.z = selHi ? b2 : a2;
      u.w = selHi ? b3 : a3;
      ap[c] = *(bf16x8*)&u;
    }

    // PV: A = P-frags (regs), B = Vt rows; C row = q-local (lg*4+reg),
    // col = d (lr). P already normalized.
#pragma unroll
    for (int ct = 0; ct < 4; ++ct) {
      f32x4 o = {};
#pragma unroll
      for (int c = 0; c < 3; ++c) {
        bf16x8 vv = *(const bf16x8*)(Vth + (size_t)(ct * 16 + lr) * 96 + c * 32 + lg * 8);
        o = __builtin_amdgcn_mfma_f32_16x16x32_bf16(ap[c], vv, o, 0, 0, 0);
      }
#pragma unroll
      for (int reg = 0; reg < 4; ++reg)
        Oq[(mbase + wr + rg * 16 + lg * 4 + reg) * 512 + nbase + wc + ct * 16 + lr] =
            f2bf(o[reg]);
    }
#pragma unroll
    for (int t = 0; t < 5; ++t) sc[t] = sn[t];
  }
}

// ---------------------------------------------------------------------------
// O-proj K-step (bf16 A+B, both slot^=((row>>1)&3)); unchanged R12.
// ---------------------------------------------------------------------------
#define KSTEP(t, boff)                                                        \
  {                                                                           \
    if ((t) < 15)                                                             \
      asm volatile("s_waitcnt vmcnt(4)" ::: "memory");                        \
    else                                                                      \
      asm volatile("s_waitcnt vmcnt(0)" ::: "memory");                        \
    __builtin_amdgcn_s_barrier();                                             \
    __builtin_amdgcn_sched_barrier(0);                                        \
    const unsigned short* bufA = smem + (boff);                               \
    const unsigned short* bufB = bufA + 4096;                                 \
    const int swB = (lr >> 1) & 3;                                            \
    bf16x8 af[4], bv8[4];                                                     \
    _Pragma("unroll") for (int m = 0; m < 4; ++m)                             \
        af[m] = *(const bf16x8*)&bufA[(wr + m * 16 + lr) * 32 +               \
                                      (lg ^ swB) * 8];                        \
    _Pragma("unroll") for (int n = 0; n < 4; ++n)                             \
        bv8[n] = *(const bf16x8*)&bufB[(wc + n * 16 + lr) * 32 +              \
                                       (lg ^ swB) * 8];                       \
    asm volatile("s_waitcnt lgkmcnt(0)" ::: "memory");                        \
    __builtin_amdgcn_sched_barrier(0);                                        \
    __builtin_amdgcn_s_barrier();                                             \
    if ((t) <= 13) {                                                          \
      int nk = ((t) + 2) * 32;                                                \
      GLDS16(gA + nk, smem + (boff) + w * 1024);                              \
      GLDS16(gA + nk + 16 * 512, smem + (boff) + w * 1024 + 512);             \
      GLDS16(gB + nk, smem + (boff) + 4096 + w * 1024);                       \
      GLDS16(gB + nk + 16 * 512, smem + (boff) + 4096 + w * 1024 + 512);      \
    }                                                                         \
    _Pragma("unroll") for (int m = 0; m < 4; ++m)                             \
        _Pragma("unroll") for (int n = 0; n < 4; ++n)                         \
            acc[m][n] = __builtin_amdgcn_mfma_f32_16x16x32_bf16(              \
                af[m], bv8[n], acc[m][n], 0, 0, 0);                           \
  }

__global__ __launch_bounds__(256) void gemm512_glds_kernel(
    const unsigned short* __restrict__ A, const unsigned short* __restrict__ BT,
    const float* __restrict__ bias, float* __restrict__ Out) {
  __shared__ __align__(16) unsigned short smem[16384];  // 32 KB
  int bid = ((blockIdx.x & 7) << 7) | (blockIdx.x >> 3);  // XCD swizzle
  size_t mbase = (size_t)(bid >> 2) * 128;
  int nbase = (bid & 3) * 128;
  int tid = threadIdx.x;
  int l = tid & 63, w = tid >> 6;
  int lr = l & 15, lg = l >> 4;
  int wr = (w >> 1) * 64, wc = (w & 1) * 64;

  const unsigned short* gA = A + (mbase + w * 32 + (l >> 2)) * 512 +
                             (((l & 3) ^ ((l >> 3) & 3))) * 8;
  const unsigned short* gB = BT + (size_t)(nbase + w * 32 + (l >> 2)) * 512 +
                             (((l & 3) ^ ((l >> 3) & 3))) * 8;

  GLDS16(gA, smem + w * 1024);
  GLDS16(gA + 16 * 512, smem + w * 1024 + 512);
  GLDS16(gB, smem + 4096 + w * 1024);
  GLDS16(gB + 16 * 512, smem + 4096 + w * 1024 + 512);
  GLDS16(gA + 32, smem + 8192 + w * 1024);
  GLDS16(gA + 32 + 16 * 512, smem + 8192 + w * 1024 + 512);
  GLDS16(gB + 32, smem + 12288 + w * 1024);
  GLDS16(gB + 32 + 16 * 512, smem + 12288 + w * 1024 + 512);

  f32x4 acc[4][4] = {};
#pragma unroll 1
  for (int t = 0; t < 16; t += 2) {
    KSTEP(t, 0);
    KSTEP(t + 1, 8192);
  }

#pragma unroll
  for (int m = 0; m < 4; ++m) {
#pragma unroll
    for (int n = 0; n < 4; ++n) {
#pragma unroll
      for (int reg = 0; reg < 4; ++reg) {
        size_t row = mbase + wr + m * 16 + lg * 4 + reg;
        int col = nbase + wc + n * 16 + lr;
        Out[row * 512 + col] = acc[m][n][reg] + bias[col];
      }
    }
  }
}

// ---------------------------------------------------------------------------
// Workspace layout (bytes)
// ---------------------------------------------------------------------------
static const size_t OFF_Q   = 0;                         // 8*4096*512*2 = 33554432
static const size_t OFF_KP  = 33554432;                  // 8*8*80*64*2  = 655360
static const size_t OFF_VT  = OFF_KP + 655360;           // 8*8*64*96*2  = 786432
static const size_t OFF_WQT = OFF_VT + 786432;           // 512*512*2
static const size_t OFF_WKT = OFF_WQT + 524288;          // 512*768*2
static const size_t OFF_WVT = OFF_WKT + 786432;          // 512*768*2
static const size_t OFF_WOT = OFF_WVT + 786432;          // 512*512*2
static const size_t WS_NEEDED = OFF_WOT + 524288;        // 37617664

extern "C" void kernel_launch(void* const* d_in, const int* in_sizes, int n_in,
                              void* d_out, int out_size, void* d_ws, size_t ws_size,
                              hipStream_t stream) {
  (void)in_sizes; (void)n_in; (void)out_size;
  if (ws_size < WS_NEEDED) return;

  const float* latent  = (const float*)d_in[0];
  const float* context = (const float*)d_in[1];
  const float* wq = (const float*)d_in[2];
  const float* bq = (const float*)d_in[3];
  const float* wk = (const float*)d_in[4];
  const float* bk = (const float*)d_in[5];
  const float* wv = (const float*)d_in[6];
  const float* bv = (const float*)d_in[7];
  const float* wo = (const float*)d_in[8];
  const float* bo = (const float*)d_in[9];
  float* out = (float*)d_out;

  char* ws = (char*)d_ws;
  unsigned short* wsQ = (unsigned short*)(ws + OFF_Q);   // attn output (bf16)
  unsigned short* Kp  = (unsigned short*)(ws + OFF_KP);
  unsigned short* Vt  = (unsigned short*)(ws + OFF_VT);
  unsigned short* wqT = (unsigned short*)(ws + OFF_WQT);
  unsigned short* wkT = (unsigned short*)(ws + OFF_WKT);
  unsigned short* wvT = (unsigned short*)(ws + OFF_WVT);
  unsigned short* woT = (unsigned short*)(ws + OFF_WOT);

  wtrans_all_kernel<<<1280 + 352, 256, 0, stream>>>(
      wq, wk, wv, wo, wqT, wkT, wvT, woT, (uint4*)(ws + OFF_KP));
  kv_proj_kernel<<<160, 256, 0, stream>>>(context, wkT, wvT, bk, bv, Kp, Vt);
  qproj_attn_kernel<<<1024, 256, 0, stream>>>(latent, wqT, bq, Kp, Vt, wsQ);
  gemm512_glds_kernel<<<1024, 256, 0, stream>>>(wsQ, woT, bo, out);
}